// Round 6
// baseline (471.517 us; speedup 1.0000x reference)
//
#include <hip/hip_runtime.h>
#include <stdint.h>

typedef short short8 __attribute__((ext_vector_type(8)));
typedef __fp16 fp16x8 __attribute__((ext_vector_type(8)));
typedef float f32x16 __attribute__((ext_vector_type(16)));
typedef unsigned int uint;

#define NREG 49
#define NQ   100
#define CC   256
#define OUT_POS_OFF 5017600        // 4*49*100*256
#define PO_PER (NQ*CC)             // 25600 floats per (bn,seg) partial
#define QF_BYTES 65536             // 64 frags * 64 lanes * 16 B (fp16)
#define MFMA_BF16 __builtin_amdgcn_mfma_f32_32x32x16_bf16
#define MFMA_F16  __builtin_amdgcn_mfma_f32_32x32x16_f16

union U4H8 { uint4 u; fp16x8 h; short8 s; };

// LDS-only barrier: global loads stay in flight across it.
#define LBAR() do { \
    asm volatile("s_waitcnt lgkmcnt(0)" ::: "memory"); \
    __builtin_amdgcn_s_barrier(); \
} while (0)

__device__ __forceinline__ uint pkrtz(float a, float b){
    auto v = __builtin_amdgcn_cvt_pkrtz(a, b);   // __fp16 x2, RTZ
    return __builtin_bit_cast(uint, v);
}
__device__ __forceinline__ uint16_t f2bf_rne(float x){
    uint u = __float_as_uint(x);
    u += 0x7fffu + ((u >> 16) & 1u);
    return (uint16_t)(u >> 16);
}
__device__ __forceinline__ float bf2f(uint16_t b){
    return __uint_as_float(((uint)b) << 16);
}

// ---------------------------------------------------------------------------
// Kernel 0: Q fragments in fp16, exact 32x32x16 B-operand order.
// frag = qt*16 + k; lane holds Q[q = qt*32 + (lane&31)][c = k*16 + (lane>>5)*8 + j]
// ---------------------------------------------------------------------------
__global__ __launch_bounds__(512) void qfrag_kernel(const float* __restrict__ Qg,
                                                    uint4* __restrict__ qf){
    int gid  = blockIdx.x * 512 + threadIdx.x;   // 0..4095
    int lane = gid & 63;
    int frag = gid >> 6;                         // 0..63
    int k    = frag & 15;
    int qt   = frag >> 4;
    int q    = qt * 32 + (lane & 31);
    int c0   = k * 16 + (lane >> 5) * 8;
    float v[8];
#pragma unroll
    for (int j = 0; j < 8; ++j) v[j] = (q < NQ) ? Qg[q * CC + c0 + j] : 0.f;
    qf[gid] = make_uint4(pkrtz(v[0], v[1]), pkrtz(v[2], v[3]),
                         pkrtz(v[4], v[5]), pkrtz(v[6], v[7]));
}

// ---------------------------------------------------------------------------
// Phase A: fused attention over an s-segment of one (b, region).
// 512 threads, 64 KB LDS. grid = 196*split.
// __launch_bounds__(512, 4): license 2 blocks/CU (4 waves/EU). Register
// budget 512/wave >> ~228 peak use -> no spills expected. Cross-block
// phase overlap is the latency-hiding mechanism (R3 showed occupancy 2x
// and hbm_gbps 1.5->2.5 TB/s; this isolates it without R3's Q-refetch).
// LDS layout (byte offsets):
//   [0, 32768)      sRT: bf16 GEMM2-B frag-order, XOR-swizzled by c-group
//   [32768, 65536)  union region:
//       phase stage/G1: sAf fp16 GEMM1-A frag-order (32 KB)
//       phase exp/G2:   sP  bf16 GEMM2-A frag-order (low 16 KB)
//       post-loop:      sL  float[128] softmax denominators
// ---------------------------------------------------------------------------
__global__ __launch_bounds__(512, 4) void attn_kernel(
        const float* __restrict__ img, const uint4* __restrict__ qf,
        float* __restrict__ out, float* __restrict__ po,
        float* __restrict__ pl, int split)
{
    __shared__ __align__(16) unsigned char smem[65536];
    unsigned char* sRT = smem;
    unsigned char* sU  = smem + 32768;

    const int tid = threadIdx.x;
    const int seg = blockIdx.x % split;
    const int bn  = blockIdx.x / split;    // 0..195
    const int rr  = bn % NREG;
    const int bb  = bn / NREG;
    const int gh  = rr / 7, gw = rr % 7;

    if (bn == 0 && seg == 0 && tid < NREG){    // positions output
        out[OUT_POS_OFF + 2 * tid]     = (float)((tid / 7) / 7.0);
        out[OUT_POS_OFF + 2 * tid + 1] = (float)((tid % 7) / 7.0);
    }

    const int lane = tid & 63, w = tid >> 6;
    const int l31  = lane & 31;
    const int st = w & 1, qt = w >> 1;     // GEMM1 roles
    const int mp = w & 1, cq = w >> 1;     // GEMM2 roles

    // staging roles: thread covers pixel sloc, columns [ct*32, ct*32+32)
    const int sloc = tid >> 3;             // 0..63
    const int ct   = tid & 7;
    const int stw  = sloc >> 5;            // sAf frag half
    const int s31  = sloc & 31;
    const int ksw  = sloc >> 4;            // sRT kstep
    const int lhw  = (sloc >> 3) & 1;
    const int jw   = sloc & 7;
    // sRT write: element i (c = ct*32+i) at rtwbase + ((i^ct)<<4)
    const int rtwbase = ((ksw * 8 + ct) * 64 + lhw * 32) * 16 + jw * 2;
    // sAf write for run r (i = 8r..8r+7): afwbase + (r>>1)*1024 + (r&1)*512
    const int afwbase = (stw * 16 + ct * 2) * 1024 + s31 * 16;

    const float* rbase = img + ((size_t)(bb * 224 + gh * 32) * 224 + gw * 32) * CC;

    // Q fragments in registers (fp16): 16 x 16B
    uint4 qr[16];
#pragma unroll
    for (int k = 0; k < 16; ++k) qr[k] = qf[(qt * 16 + k) * 64 + lane];

    f32x16 acc00, acc01, acc10, acc11;
#pragma unroll
    for (int i = 0; i < 16; ++i){ acc00[i]=0.f; acc01[i]=0.f; acc10[i]=0.f; acc11[i]=0.f; }
    float lp = 0.f;
    const int qq = qt * 32 + l31;

    const int nch = 16 / split;
    const int ch0 = seg * nch, ch1 = ch0 + nch;

    float4 rb[8], rb2[8];
    {   // preload first chunk
        int p = ch0 * 64 + sloc;
        const float* gp = rbase + ((p >> 5) * 224 + (p & 31)) * CC + ct * 32;
#pragma unroll
        for (int j = 0; j < 8; ++j) rb[j] = *(const float4*)(gp + j * 4);
    }

    for (int ch = ch0; ch < ch1; ++ch){
        // ---- stage: rb -> sAf (fp16 frag-order) + sRT (bf16, swizzled) ----
#pragma unroll
        for (int r = 0; r < 4; ++r){
            uint4 o = make_uint4(pkrtz(rb[2*r].x,   rb[2*r].y),
                                 pkrtz(rb[2*r].z,   rb[2*r].w),
                                 pkrtz(rb[2*r+1].x, rb[2*r+1].y),
                                 pkrtz(rb[2*r+1].z, rb[2*r+1].w));
            *(uint4*)(sU + afwbase + ((r >> 1) * 1024) + ((r & 1) * 512)) = o;
        }
#pragma unroll
        for (int i = 0; i < 32; ++i){
            const float* fp = (const float*)rb;
            uint u = __float_as_uint(fp[i]);
            *(uint16_t*)(sRT + rtwbase + ((i ^ ct) << 4)) = (uint16_t)(u >> 16);
        }

        // ---- prefetch next chunk (stays in flight across raw barriers) ----
        if (ch + 1 < ch1){
            int p = (ch + 1) * 64 + sloc;
            const float* gp = rbase + ((p >> 5) * 224 + (p & 31)) * CC + ct * 32;
#pragma unroll
            for (int j = 0; j < 8; ++j) rb2[j] = *(const float4*)(gp + j * 4);
        }
        LBAR();   // B1: staged LDS data visible (vmcnt NOT drained)

        // ---- GEMM1 (fp16): scoresT[s][q], wave (st, qt) ----
        f32x16 a1;
#pragma unroll
        for (int i = 0; i < 16; ++i) a1[i] = 0.f;
#pragma unroll
        for (int k = 0; k < 16; ++k){
            U4H8 af; af.u = *(const uint4*)(sU + ((st * 16 + k) * 64 + lane) * 16);
            U4H8 bq; bq.u = qr[k];
            a1 = MFMA_F16(af.h, bq.h, a1, 0, 0, 0);
        }
        LBAR();   // B2: GEMM1 reads of sAf done before sP overwrites

        // ---- exp(score-40) -> bf16 sP (GEMM2-A frag-order), accumulate l ----
        // C/D map: col=q=lane&31, row=s_local=(reg&3)+8*(reg>>2)+4*(lane>>5)
#pragma unroll
        for (int g2 = 0; g2 < 4; ++g2){
            uint16_t e[4];
#pragma unroll
            for (int r2 = 0; r2 < 4; ++r2){
                float sc = a1[g2 * 4 + r2];
                float pv = exp2f(sc * 1.4426950408889634f - 57.70780163555852f);
                e[r2] = f2bf_rne(pv);
                lp += bf2f(e[r2]);
            }
            int kst = st * 2 + (g2 >> 1);
            int boff = ((kst * 4 + qt) * 64 + (g2 & 1) * 32 + l31) * 16 + (lane >> 5) * 8;
            *(uint2*)(sU + boff) = make_uint2((uint)e[0] | ((uint)e[1] << 16),
                                              (uint)e[2] | ((uint)e[3] << 16));
        }
        LBAR();   // B3: sP visible

        // ---- GEMM2 (bf16): O[q][c] += P * R, wave (mp, cq) ----
#pragma unroll
        for (int ks = 0; ks < 4; ++ks){
            U4H8 A0, A1, B0, B1;
            A0.u = *(const uint4*)(sU  + ((ks * 4 + mp * 2    ) * 64 + lane) * 16);
            A1.u = *(const uint4*)(sU  + ((ks * 4 + mp * 2 + 1) * 64 + lane) * 16);
            B0.u = *(const uint4*)(sRT + ((ks * 8 + cq * 2    ) * 64 + (lane ^ (cq * 2    ))) * 16);
            B1.u = *(const uint4*)(sRT + ((ks * 8 + cq * 2 + 1) * 64 + (lane ^ (cq * 2 + 1))) * 16);
            acc00 = MFMA_BF16(A0.s, B0.s, acc00, 0, 0, 0);
            acc01 = MFMA_BF16(A0.s, B1.s, acc01, 0, 0, 0);
            acc10 = MFMA_BF16(A1.s, B0.s, acc10, 0, 0, 0);
            acc11 = MFMA_BF16(A1.s, B1.s, acc11, 0, 0, 0);
        }
        LBAR();   // B4: GEMM2 reads done before next stage writes

        if (ch + 1 < ch1){
#pragma unroll
            for (int j = 0; j < 8; ++j) rb[j] = rb2[j];
        }
    }

    // ---- softmax denominators via LDS (aliased region, re-initialized) ----
    float* sL = (float*)sU;
    if (tid < 128) sL[tid] = 0.f;
    __syncthreads();
    atomicAdd(&sL[qq], lp);
    __syncthreads();

    const int c0 = cq * 64 + l31;
    if (split == 1){
        float* ob = out + (size_t)bn * PO_PER;
#pragma unroll
        for (int r = 0; r < 16; ++r){
            int row = (r & 3) + 8 * (r >> 2) + 4 * (lane >> 5);
            int q0 = mp * 64 + row, q1 = q0 + 32;
            if (q0 < NQ){
                float inv = 1.0f / sL[q0];
                ob[q0 * CC + c0]      = acc00[r] * inv;
                ob[q0 * CC + c0 + 32] = acc01[r] * inv;
            }
            if (q1 < NQ){
                float inv = 1.0f / sL[q1];
                ob[q1 * CC + c0]      = acc10[r] * inv;
                ob[q1 * CC + c0 + 32] = acc11[r] * inv;
            }
        }
    } else {
        float* ob = po + ((size_t)bn * split + seg) * PO_PER;
#pragma unroll
        for (int r = 0; r < 16; ++r){
            int row = (r & 3) + 8 * (r >> 2) + 4 * (lane >> 5);
            int q0 = mp * 64 + row, q1 = q0 + 32;
            if (q0 < NQ){
                ob[q0 * CC + c0]      = acc00[r];
                ob[q0 * CC + c0 + 32] = acc01[r];
            }
            if (q1 < NQ){
                ob[q1 * CC + c0]      = acc10[r];
                ob[q1 * CC + c0 + 32] = acc11[r];
            }
        }
        if (tid < 128) pl[((size_t)bn * split + seg) * 128 + tid] = sL[tid];
    }
}

// ---------------------------------------------------------------------------
// Phase B: sum partials across segments, normalize, write out.
// grid = 392 (2 wgs per bn), 512 threads.
// ---------------------------------------------------------------------------
__global__ __launch_bounds__(512) void reduce_kernel(
        const float* __restrict__ po, const float* __restrict__ pl,
        float* __restrict__ out, int split)
{
    __shared__ float sInv[64];
    const int bn = blockIdx.x >> 1, hf = blockIdx.x & 1, tid = threadIdx.x;
    if (tid < 50){
        int q = hf * 50 + tid;
        float s = 0.f;
        for (int g = 0; g < split; ++g)
            s += pl[((size_t)bn * split + g) * 128 + q];
        sInv[tid] = 1.0f / s;
    }
    __syncthreads();
    const float* base = po + (size_t)bn * split * PO_PER;
    float* ob = out + (size_t)bn * PO_PER;
#pragma unroll 1
    for (int i = 0; i < 25; ++i){
        int idx = hf * 12800 + i * 512 + tid;
        float s = 0.f;
        for (int g = 0; g < split; ++g) s += base[g * PO_PER + idx];
        ob[idx] = s * sInv[(idx >> 8) - hf * 50];
    }
}

extern "C" void kernel_launch(void* const* d_in, const int* in_sizes, int n_in,
                              void* d_out, int out_size, void* d_ws, size_t ws_size,
                              hipStream_t stream){
    const float* img = (const float*)d_in[0];
    const float* Qg  = (const float*)d_in[1];
    float* out = (float*)d_out;

    uint4* qf = (uint4*)d_ws;
    qfrag_kernel<<<8, 512, 0, stream>>>(Qg, qf);

    int split = 1;
    const size_t per_seg = (size_t)196 * (PO_PER + 128) * sizeof(float);
    if (ws_size >= QF_BYTES + 4 * per_seg) split = 4;

    float *po = nullptr, *pl = nullptr;
    if (split > 1){
        po = (float*)((char*)d_ws + QF_BYTES);
        pl = po + (size_t)196 * split * PO_PER;
    }

    attn_kernel<<<196 * split, 512, 0, stream>>>(img, qf, out, po, pl, split);
    if (split > 1)
        reduce_kernel<<<392, 512, 0, stream>>>(po, pl, out, split);
}

// Round 7
// 376.007 us; speedup vs baseline: 1.2540x; 1.2540x over previous
//
#include <hip/hip_runtime.h>
#include <stdint.h>

typedef short short8 __attribute__((ext_vector_type(8)));
typedef __fp16 fp16x8 __attribute__((ext_vector_type(8)));
typedef float f32x16 __attribute__((ext_vector_type(16)));
typedef unsigned int uint;

#define NREG 49
#define NQ   100
#define CC   256
#define OUT_POS_OFF 5017600        // 4*49*100*256
#define PO_PER (NQ*CC)             // 25600 floats per (bn,seg) partial
#define QF_BYTES 65536             // 64 frags * 64 lanes * 16 B (fp16)
#define MFMA_BF16 __builtin_amdgcn_mfma_f32_32x32x16_bf16
#define MFMA_F16  __builtin_amdgcn_mfma_f32_32x32x16_f16

union U4H8 { uint4 u; fp16x8 h; short8 s; };

// LDS-only barrier: global loads stay in flight across it.
#define LBAR() do { \
    asm volatile("s_waitcnt lgkmcnt(0)" ::: "memory"); \
    __builtin_amdgcn_s_barrier(); \
} while (0)

__device__ __forceinline__ uint pkrtz(float a, float b){
    auto v = __builtin_amdgcn_cvt_pkrtz(a, b);   // __fp16 x2, RTZ
    return __builtin_bit_cast(uint, v);
}
__device__ __forceinline__ uint16_t f2bf_rne(float x){
    uint u = __float_as_uint(x);
    u += 0x7fffu + ((u >> 16) & 1u);
    return (uint16_t)(u >> 16);
}
__device__ __forceinline__ float bf2f(uint16_t b){
    return __uint_as_float(((uint)b) << 16);
}

// ---------------------------------------------------------------------------
// Kernel 0: Q fragments in fp16, exact 32x32x16 B-operand order.
// frag = qt*16 + k; lane holds Q[q = qt*32 + (lane&31)][c = k*16 + (lane>>5)*8 + j]
// ---------------------------------------------------------------------------
__global__ __launch_bounds__(512) void qfrag_kernel(const float* __restrict__ Qg,
                                                    uint4* __restrict__ qf){
    int gid  = blockIdx.x * 512 + threadIdx.x;   // 0..4095
    int lane = gid & 63;
    int frag = gid >> 6;                         // 0..63
    int k    = frag & 15;
    int qt   = frag >> 4;
    int q    = qt * 32 + (lane & 31);
    int c0   = k * 16 + (lane >> 5) * 8;
    float v[8];
#pragma unroll
    for (int j = 0; j < 8; ++j) v[j] = (q < NQ) ? Qg[q * CC + c0 + j] : 0.f;
    qf[gid] = make_uint4(pkrtz(v[0], v[1]), pkrtz(v[2], v[3]),
                         pkrtz(v[4], v[5]), pkrtz(v[6], v[7]));
}

// ---------------------------------------------------------------------------
// Phase A: fused attention over an s-segment of one (b, region).
// 512 threads, 144 KB LDS (chunk-parity double buffers), 1 wg/CU. grid=196*split.
// LDS layout:
//   [0,      65536)  sAf[2]: fp16 GEMM1-A frag-order, 32 KB per parity
//   [65536, 131072)  sRT[2]: bf16 GEMM2-B frag-order (XOR-swizzled), 32 KB per parity
//   [131072,147456)  sP: bf16 GEMM2-A frag-order, 16 KB (single; B1 guards reuse)
//   sL (softmax denoms) aliases sP after the loop.
// Pipeline per chunk (2 barriers, was 4):
//   B1; G1(p)+exp -> sP; B2; G2(p) interleaved with stage(ch+1 -> p^1)
// Hazards covered by parity + barrier ordering (see round notes).
// ---------------------------------------------------------------------------
__global__ __launch_bounds__(512, 2) void attn_kernel(
        const float* __restrict__ img, const uint4* __restrict__ qf,
        float* __restrict__ out, float* __restrict__ po,
        float* __restrict__ pl, int split)
{
    __shared__ __align__(16) unsigned char smem[147456];
    unsigned char* sP = smem + 131072;

    const int tid = threadIdx.x;
    const int seg = blockIdx.x % split;
    const int bn  = blockIdx.x / split;    // 0..195
    const int rr  = bn % NREG;
    const int bb  = bn / NREG;
    const int gh  = rr / 7, gw = rr % 7;

    if (bn == 0 && seg == 0 && tid < NREG){    // positions output
        out[OUT_POS_OFF + 2 * tid]     = (float)((tid / 7) / 7.0);
        out[OUT_POS_OFF + 2 * tid + 1] = (float)((tid % 7) / 7.0);
    }

    const int lane = tid & 63, w = tid >> 6;
    const int l31  = lane & 31;
    const int st = w & 1, qt = w >> 1;     // GEMM1 roles
    const int mp = w & 1, cq = w >> 1;     // GEMM2 roles

    // staging roles: thread covers pixel sloc, columns [ct*32, ct*32+32)
    const int sloc = tid >> 3;             // 0..63
    const int ct   = tid & 7;
    const int stw  = sloc >> 5;            // sAf frag half
    const int s31  = sloc & 31;
    const int ksw  = sloc >> 4;            // sRT kstep
    const int lhw  = (sloc >> 3) & 1;
    const int jw   = sloc & 7;
    // sRT write: element i (c = ct*32+i) at rtwbase + ((i^ct)<<4)
    const int rtwbase = ((ksw * 8 + ct) * 64 + lhw * 32) * 16 + jw * 2;
    // sAf write for run r (i = 8r..8r+7): afwbase + (r>>1)*1024 + (r&1)*512
    const int afwbase = (stw * 16 + ct * 2) * 1024 + s31 * 16;

    const float* rbase = img + ((size_t)(bb * 224 + gh * 32) * 224 + gw * 32) * CC;

    // Q fragments in registers (fp16): 16 x 16B
    uint4 qr[16];
#pragma unroll
    for (int k = 0; k < 16; ++k) qr[k] = qf[(qt * 16 + k) * 64 + lane];

    f32x16 acc00, acc01, acc10, acc11;
#pragma unroll
    for (int i = 0; i < 16; ++i){ acc00[i]=0.f; acc01[i]=0.f; acc10[i]=0.f; acc11[i]=0.f; }
    float lp = 0.f;
    const int qq = qt * 32 + l31;

    const int nch = 16 / split;
    const int ch0 = seg * nch, ch1 = ch0 + nch;

    float4 rb[8];
    {   // preload chunk ch0
        int p = ch0 * 64 + sloc;
        const float* gp = rbase + ((p >> 5) * 224 + (p & 31)) * CC + ct * 32;
#pragma unroll
        for (int j = 0; j < 8; ++j) rb[j] = *(const float4*)(gp + j * 4);
    }

    // ---- prologue: stage chunk ch0 into parity 0; issue loads for ch0+1 ----
    {
        unsigned char* sAf = smem;
        unsigned char* sRT = smem + 65536;
#pragma unroll
        for (int r = 0; r < 4; ++r){
            uint4 o = make_uint4(pkrtz(rb[2*r].x,   rb[2*r].y),
                                 pkrtz(rb[2*r].z,   rb[2*r].w),
                                 pkrtz(rb[2*r+1].x, rb[2*r+1].y),
                                 pkrtz(rb[2*r+1].z, rb[2*r+1].w));
            *(uint4*)(sAf + afwbase + ((r >> 1) * 1024) + ((r & 1) * 512)) = o;
        }
#pragma unroll
        for (int i = 0; i < 32; ++i){
            const float* fp = (const float*)rb;
            uint u = __float_as_uint(fp[i]);
            *(uint16_t*)(sRT + rtwbase + ((i ^ ct) << 4)) = (uint16_t)(u >> 16);
        }
        if (ch0 + 1 < ch1){
            int p = (ch0 + 1) * 64 + sloc;
            const float* gp = rbase + ((p >> 5) * 224 + (p & 31)) * CC + ct * 32;
#pragma unroll
            for (int j = 0; j < 8; ++j) rb[j] = *(const float4*)(gp + j * 4);
        }
    }

    int par = 0;
    for (int ch = ch0; ch < ch1; ++ch){
        unsigned char* sAf = smem + (par << 15);
        unsigned char* sRT = smem + 65536 + (par << 15);
        unsigned char* sAfN = smem + ((par ^ 1) << 15);
        unsigned char* sRTN = smem + 65536 + ((par ^ 1) << 15);

        LBAR();   // B1: sAf/sRT(par) staged data visible; also guards sP reuse

        // ---- GEMM1 (fp16): scoresT[s][q], wave (st, qt) ----
        f32x16 a1;
#pragma unroll
        for (int i = 0; i < 16; ++i) a1[i] = 0.f;
#pragma unroll
        for (int k = 0; k < 16; ++k){
            U4H8 af; af.u = *(const uint4*)(sAf + ((st * 16 + k) * 64 + lane) * 16);
            U4H8 bq; bq.u = qr[k];
            a1 = MFMA_F16(af.h, bq.h, a1, 0, 0, 0);
        }

        // ---- exp(score-40) -> bf16 sP (GEMM2-A frag-order), accumulate l ----
        // C/D map: col=q=lane&31, row=s_local=(reg&3)+8*(reg>>2)+4*(lane>>5)
#pragma unroll
        for (int g2 = 0; g2 < 4; ++g2){
            uint16_t e[4];
#pragma unroll
            for (int r2 = 0; r2 < 4; ++r2){
                float sc = a1[g2 * 4 + r2];
                float pv = exp2f(sc * 1.4426950408889634f - 57.70780163555852f);
                e[r2] = f2bf_rne(pv);
                lp += bf2f(e[r2]);
            }
            int kst = st * 2 + (g2 >> 1);
            int boff = ((kst * 4 + qt) * 64 + (g2 & 1) * 32 + l31) * 16 + (lane >> 5) * 8;
            *(uint2*)(sP + boff) = make_uint2((uint)e[0] | ((uint)e[1] << 16),
                                              (uint)e[2] | ((uint)e[3] << 16));
        }

        LBAR();   // B2: sP visible

        // ---- GEMM2 (bf16) interleaved with stage(ch+1 -> par^1) ----
        // Both live in one barrier-free region: independent work for ILP.
#pragma unroll
        for (int ks = 0; ks < 4; ++ks){
            U4H8 A0, A1, B0, B1;
            A0.u = *(const uint4*)(sP  + ((ks * 4 + mp * 2    ) * 64 + lane) * 16);
            A1.u = *(const uint4*)(sP  + ((ks * 4 + mp * 2 + 1) * 64 + lane) * 16);
            B0.u = *(const uint4*)(sRT + ((ks * 8 + cq * 2    ) * 64 + (lane ^ (cq * 2    ))) * 16);
            B1.u = *(const uint4*)(sRT + ((ks * 8 + cq * 2 + 1) * 64 + (lane ^ (cq * 2 + 1))) * 16);
            acc00 = MFMA_BF16(A0.s, B0.s, acc00, 0, 0, 0);
            acc01 = MFMA_BF16(A0.s, B1.s, acc01, 0, 0, 0);
            acc10 = MFMA_BF16(A1.s, B0.s, acc10, 0, 0, 0);
            acc11 = MFMA_BF16(A1.s, B1.s, acc11, 0, 0, 0);
        }

        if (ch + 1 < ch1){
            // stage chunk ch+1 into the other parity (regions untouched by
            // this chunk's reads -> no barrier needed before these writes)
#pragma unroll
            for (int r = 0; r < 4; ++r){
                uint4 o = make_uint4(pkrtz(rb[2*r].x,   rb[2*r].y),
                                     pkrtz(rb[2*r].z,   rb[2*r].w),
                                     pkrtz(rb[2*r+1].x, rb[2*r+1].y),
                                     pkrtz(rb[2*r+1].z, rb[2*r+1].w));
                *(uint4*)(sAfN + afwbase + ((r >> 1) * 1024) + ((r & 1) * 512)) = o;
            }
#pragma unroll
            for (int i = 0; i < 32; ++i){
                const float* fp = (const float*)rb;
                uint u = __float_as_uint(fp[i]);
                *(uint16_t*)(sRTN + rtwbase + ((i ^ ct) << 4)) = (uint16_t)(u >> 16);
            }
            // issue global loads for chunk ch+2 (consumed one iteration later)
            if (ch + 2 < ch1){
                int p = (ch + 2) * 64 + sloc;
                const float* gp = rbase + ((p >> 5) * 224 + (p & 31)) * CC + ct * 32;
#pragma unroll
                for (int j = 0; j < 8; ++j) rb[j] = *(const float4*)(gp + j * 4);
            }
        }
        par ^= 1;
    }

    __syncthreads();   // all GEMM2 reads of sP done before sL aliases it

    // ---- softmax denominators via LDS (aliases sP) ----
    float* sL = (float*)sP;
    if (tid < 128) sL[tid] = 0.f;
    __syncthreads();
    atomicAdd(&sL[qq], lp);
    __syncthreads();

    const int c0 = cq * 64 + l31;
    if (split == 1){
        float* ob = out + (size_t)bn * PO_PER;
#pragma unroll
        for (int r = 0; r < 16; ++r){
            int row = (r & 3) + 8 * (r >> 2) + 4 * (lane >> 5);
            int q0 = mp * 64 + row, q1 = q0 + 32;
            if (q0 < NQ){
                float inv = 1.0f / sL[q0];
                ob[q0 * CC + c0]      = acc00[r] * inv;
                ob[q0 * CC + c0 + 32] = acc01[r] * inv;
            }
            if (q1 < NQ){
                float inv = 1.0f / sL[q1];
                ob[q1 * CC + c0]      = acc10[r] * inv;
                ob[q1 * CC + c0 + 32] = acc11[r] * inv;
            }
        }
    } else {
        float* ob = po + ((size_t)bn * split + seg) * PO_PER;
#pragma unroll
        for (int r = 0; r < 16; ++r){
            int row = (r & 3) + 8 * (r >> 2) + 4 * (lane >> 5);
            int q0 = mp * 64 + row, q1 = q0 + 32;
            if (q0 < NQ){
                ob[q0 * CC + c0]      = acc00[r];
                ob[q0 * CC + c0 + 32] = acc01[r];
            }
            if (q1 < NQ){
                ob[q1 * CC + c0]      = acc10[r];
                ob[q1 * CC + c0 + 32] = acc11[r];
            }
        }
        if (tid < 128) pl[((size_t)bn * split + seg) * 128 + tid] = sL[tid];
    }
}

// ---------------------------------------------------------------------------
// Phase B: sum partials across segments, normalize, write out.
// grid = 392 (2 wgs per bn), 512 threads.
// ---------------------------------------------------------------------------
__global__ __launch_bounds__(512) void reduce_kernel(
        const float* __restrict__ po, const float* __restrict__ pl,
        float* __restrict__ out, int split)
{
    __shared__ float sInv[64];
    const int bn = blockIdx.x >> 1, hf = blockIdx.x & 1, tid = threadIdx.x;
    if (tid < 50){
        int q = hf * 50 + tid;
        float s = 0.f;
        for (int g = 0; g < split; ++g)
            s += pl[((size_t)bn * split + g) * 128 + q];
        sInv[tid] = 1.0f / s;
    }
    __syncthreads();
    const float* base = po + (size_t)bn * split * PO_PER;
    float* ob = out + (size_t)bn * PO_PER;
#pragma unroll 1
    for (int i = 0; i < 25; ++i){
        int idx = hf * 12800 + i * 512 + tid;
        float s = 0.f;
        for (int g = 0; g < split; ++g) s += base[g * PO_PER + idx];
        ob[idx] = s * sInv[(idx >> 8) - hf * 50];
    }
}

extern "C" void kernel_launch(void* const* d_in, const int* in_sizes, int n_in,
                              void* d_out, int out_size, void* d_ws, size_t ws_size,
                              hipStream_t stream){
    const float* img = (const float*)d_in[0];
    const float* Qg  = (const float*)d_in[1];
    float* out = (float*)d_out;

    uint4* qf = (uint4*)d_ws;
    qfrag_kernel<<<8, 512, 0, stream>>>(Qg, qf);

    int split = 1;
    const size_t per_seg = (size_t)196 * (PO_PER + 128) * sizeof(float);
    if (ws_size >= QF_BYTES + 4 * per_seg) split = 4;

    float *po = nullptr, *pl = nullptr;
    if (split > 1){
        po = (float*)((char*)d_ws + QF_BYTES);
        pl = po + (size_t)196 * split * PO_PER;
    }

    attn_kernel<<<196 * split, 512, 0, stream>>>(img, qf, out, po, pl, split);
    if (split > 1)
        reduce_kernel<<<392, 512, 0, stream>>>(po, pl, out, split);
}

// Round 8
// 354.128 us; speedup vs baseline: 1.3315x; 1.0618x over previous
//
#include <hip/hip_runtime.h>
#include <stdint.h>

typedef short short8 __attribute__((ext_vector_type(8)));
typedef __fp16 fp16x8 __attribute__((ext_vector_type(8)));
typedef float f32x16 __attribute__((ext_vector_type(16)));
typedef unsigned int uint;

#define NREG 49
#define NQ   100
#define CC   256
#define OUT_POS_OFF 5017600        // 4*49*100*256
#define PO_PER (NQ*CC)             // 25600 floats per (bn,seg) partial
#define QF_BYTES 65536             // 64 frags * 64 lanes * 16 B (fp16)
#define MFMA_BF16 __builtin_amdgcn_mfma_f32_32x32x16_bf16
#define MFMA_F16  __builtin_amdgcn_mfma_f32_32x32x16_f16

union U4H8 { uint4 u; fp16x8 h; short8 s; };

// LDS-only barrier: global loads stay in flight across it.
#define LBAR() do { \
    asm volatile("s_waitcnt lgkmcnt(0)" ::: "memory"); \
    __builtin_amdgcn_s_barrier(); \
} while (0)

__device__ __forceinline__ uint pkrtz(float a, float b){
    auto v = __builtin_amdgcn_cvt_pkrtz(a, b);   // __fp16 x2, RTZ
    return __builtin_bit_cast(uint, v);
}
__device__ __forceinline__ uint16_t f2bf_rne(float x){
    uint u = __float_as_uint(x);
    u += 0x7fffu + ((u >> 16) & 1u);
    return (uint16_t)(u >> 16);
}
__device__ __forceinline__ float bf2f(uint16_t b){
    return __uint_as_float(((uint)b) << 16);
}

// ---------------------------------------------------------------------------
// Kernel 0: Q fragments in fp16, exact 32x32x16 B-operand order.
// frag = qt*16 + k; lane holds Q[q = qt*32 + (lane&31)][c = k*16 + (lane>>5)*8 + j]
// ---------------------------------------------------------------------------
__global__ __launch_bounds__(512) void qfrag_kernel(const float* __restrict__ Qg,
                                                    uint4* __restrict__ qf){
    int gid  = blockIdx.x * 512 + threadIdx.x;   // 0..4095
    int lane = gid & 63;
    int frag = gid >> 6;                         // 0..63
    int k    = frag & 15;
    int qt   = frag >> 4;
    int q    = qt * 32 + (lane & 31);
    int c0   = k * 16 + (lane >> 5) * 8;
    float v[8];
#pragma unroll
    for (int j = 0; j < 8; ++j) v[j] = (q < NQ) ? Qg[q * CC + c0 + j] : 0.f;
    qf[gid] = make_uint4(pkrtz(v[0], v[1]), pkrtz(v[2], v[3]),
                         pkrtz(v[4], v[5]), pkrtz(v[6], v[7]));
}

// ---------------------------------------------------------------------------
// Phase A: fused attention over an s-segment of one (b, region).
// 512 threads, 1 wg/CU (64 KB LDS). grid = 196*split.
// COALESCED GLOBAL LOADS: wave-instruction j reads ONE pixel's 1 KB
// contiguously (lane l -> channels 4l..4l+3). Thread holds 8 pixels
// (p = j*8 + w, stride 8) x 4 channels. 16 cache lines/instr, each
// touched once (was: 64 lines/instr, each x4 via L1).
// LDS layout (byte offsets):
//   [0, 32768)      sRT: bf16 GEMM2-B frag-order, XOR-swizzled by c-group
//   [32768, 65536)  union region:
//       phase stage/G1: sAf fp16 GEMM1-A frag-order (32 KB), XOR-swizzled
//                       by (k&7)<<4 (matched in GEMM1 reads)
//       phase exp/G2:   sP  bf16 GEMM2-A frag-order (low 16 KB)
//       post-loop:      sL  float[128] softmax denominators
// ---------------------------------------------------------------------------
__global__ __launch_bounds__(512, 2) void attn_kernel(
        const float* __restrict__ img, const uint4* __restrict__ qf,
        float* __restrict__ out, float* __restrict__ po,
        float* __restrict__ pl, int split)
{
    __shared__ __align__(16) unsigned char smem[65536];
    unsigned char* sRT = smem;
    unsigned char* sU  = smem + 32768;

    const int tid = threadIdx.x;
    const int seg = blockIdx.x % split;
    const int bn  = blockIdx.x / split;    // 0..195
    const int rr  = bn % NREG;
    const int bb  = bn / NREG;
    const int gh  = rr / 7, gw = rr % 7;

    if (bn == 0 && seg == 0 && tid < NREG){    // positions output
        out[OUT_POS_OFF + 2 * tid]     = (float)((tid / 7) / 7.0);
        out[OUT_POS_OFF + 2 * tid + 1] = (float)((tid % 7) / 7.0);
    }

    const int lane = tid & 63, w = tid >> 6;
    const int l31  = lane & 31;
    const int st = w & 1, qt = w >> 1;     // GEMM1 roles
    const int mp = w & 1, cq = w >> 1;     // GEMM2 roles

    // ---- staging roles (coalesced ownership) ----
    // sAf: channel group kA = lane>>2 (16 channels each frag), this thread's
    //      4 channels start at 4*lane; b64 half selected by lane&1.
    const int kA    = lane >> 2;                       // 0..15 == frag&15
    const int aInP  = 32 * ((lane >> 1) & 1) * 16 + (lane & 1) * 8;
    const int aSwz  = (kA & 7) << 4;
    // sRT: c-tile cb = lane>>3; c&31 base = 4*(lane&7); byte = w*2
    const int cb    = lane >> 3;                       // 0..7
    const int c31b  = 4 * (lane & 7);

    const float* rbase = img + ((size_t)(bb * 224 + gh * 32) * 224 + gw * 32) * CC;

    // Q fragments in registers (fp16): 16 x 16B
    uint4 qr[16];
#pragma unroll
    for (int k = 0; k < 16; ++k) qr[k] = qf[(qt * 16 + k) * 64 + lane];

    f32x16 acc00, acc01, acc10, acc11;
#pragma unroll
    for (int i = 0; i < 16; ++i){ acc00[i]=0.f; acc01[i]=0.f; acc10[i]=0.f; acc11[i]=0.f; }
    float lp = 0.f;
    const int qq = qt * 32 + l31;

    const int nch = 16 / split;
    const int ch0 = seg * nch, ch1 = ch0 + nch;

    float4 rb[8], rb2[8];
    {   // preload first chunk: instruction j = one pixel, fully coalesced
#pragma unroll
        for (int j = 0; j < 8; ++j){
            int p = ch0 * 64 + j * 8 + w;
            rb[j] = *(const float4*)(rbase + ((p >> 5) * 224 + (p & 31)) * CC + 4 * lane);
        }
    }

    for (int ch = ch0; ch < ch1; ++ch){
        // ---- stage: rb -> sAf (fp16, b64 swizzled) + sRT (bf16 scatter) ----
#pragma unroll
        for (int j = 0; j < 8; ++j){
            int pl_ = j * 8 + w;                       // local pixel 0..63
            // sAf: frag = (pl>>5)*16 + kA
            int frag  = (pl_ >> 5) * 16 + kA;
            int inner = (((pl_ & 31) * 16 + aInP)) ^ aSwz;
            uint2 val = make_uint2(pkrtz(rb[j].x, rb[j].y), pkrtz(rb[j].z, rb[j].w));
            *(uint2*)(sU + frag * 1024 + inner) = val;
            // sRT: frag_rt = (j>>1)*8 + cb; lane_f = ((c&31)^cb) + 32*(j&1)
            const float* fv = (const float*)&rb[j];
            int fbase = ((j >> 1) * 8 + cb) * 1024 + (j & 1) * 512 + w * 2;
#pragma unroll
            for (int cc = 0; cc < 4; ++cc){
                uint u = __float_as_uint(fv[cc]);
                *(uint16_t*)(sRT + fbase + (((c31b + cc) ^ cb) << 4)) = (uint16_t)(u >> 16);
            }
        }

        // ---- prefetch next chunk (coalesced; in flight across barriers) ----
        if (ch + 1 < ch1){
#pragma unroll
            for (int j = 0; j < 8; ++j){
                int p = (ch + 1) * 64 + j * 8 + w;
                rb2[j] = *(const float4*)(rbase + ((p >> 5) * 224 + (p & 31)) * CC + 4 * lane);
            }
        }
        LBAR();   // B1: staged LDS data visible (vmcnt NOT drained)

        // ---- GEMM1 (fp16): scoresT[s][q], wave (st, qt) ----
        f32x16 a1;
#pragma unroll
        for (int i = 0; i < 16; ++i) a1[i] = 0.f;
#pragma unroll
        for (int k = 0; k < 16; ++k){
            U4H8 af; af.u = *(const uint4*)(sU + (st * 16 + k) * 1024 + ((lane * 16) ^ ((k & 7) << 4)));
            U4H8 bq; bq.u = qr[k];
            a1 = MFMA_F16(af.h, bq.h, a1, 0, 0, 0);
        }
        LBAR();   // B2: GEMM1 reads of sAf done before sP overwrites

        // ---- exp(score-40) -> bf16 sP (GEMM2-A frag-order), accumulate l ----
        // C/D map: col=q=lane&31, row=s_local=(reg&3)+8*(reg>>2)+4*(lane>>5)
#pragma unroll
        for (int g2 = 0; g2 < 4; ++g2){
            uint16_t e[4];
#pragma unroll
            for (int r2 = 0; r2 < 4; ++r2){
                float sc = a1[g2 * 4 + r2];
                float pv = exp2f(sc * 1.4426950408889634f - 57.70780163555852f);
                e[r2] = f2bf_rne(pv);
                lp += bf2f(e[r2]);
            }
            int kst = st * 2 + (g2 >> 1);
            int boff = ((kst * 4 + qt) * 64 + (g2 & 1) * 32 + l31) * 16 + (lane >> 5) * 8;
            *(uint2*)(sU + boff) = make_uint2((uint)e[0] | ((uint)e[1] << 16),
                                              (uint)e[2] | ((uint)e[3] << 16));
        }
        LBAR();   // B3: sP visible

        // ---- GEMM2 (bf16): O[q][c] += P * R, wave (mp, cq) ----
#pragma unroll
        for (int ks = 0; ks < 4; ++ks){
            U4H8 A0, A1, B0, B1;
            A0.u = *(const uint4*)(sU  + ((ks * 4 + mp * 2    ) * 64 + lane) * 16);
            A1.u = *(const uint4*)(sU  + ((ks * 4 + mp * 2 + 1) * 64 + lane) * 16);
            B0.u = *(const uint4*)(sRT + ((ks * 8 + cq * 2    ) * 64 + (lane ^ (cq * 2    ))) * 16);
            B1.u = *(const uint4*)(sRT + ((ks * 8 + cq * 2 + 1) * 64 + (lane ^ (cq * 2 + 1))) * 16);
            acc00 = MFMA_BF16(A0.s, B0.s, acc00, 0, 0, 0);
            acc01 = MFMA_BF16(A0.s, B1.s, acc01, 0, 0, 0);
            acc10 = MFMA_BF16(A1.s, B0.s, acc10, 0, 0, 0);
            acc11 = MFMA_BF16(A1.s, B1.s, acc11, 0, 0, 0);
        }
        LBAR();   // B4: GEMM2 reads done before next stage writes

        if (ch + 1 < ch1){
#pragma unroll
            for (int j = 0; j < 8; ++j) rb[j] = rb2[j];
        }
    }

    // ---- softmax denominators via LDS (aliased region, re-initialized) ----
    float* sL = (float*)sU;
    if (tid < 128) sL[tid] = 0.f;
    __syncthreads();
    atomicAdd(&sL[qq], lp);
    __syncthreads();

    const int c0 = cq * 64 + l31;
    if (split == 1){
        float* ob = out + (size_t)bn * PO_PER;
#pragma unroll
        for (int r = 0; r < 16; ++r){
            int row = (r & 3) + 8 * (r >> 2) + 4 * (lane >> 5);
            int q0 = mp * 64 + row, q1 = q0 + 32;
            if (q0 < NQ){
                float inv = 1.0f / sL[q0];
                ob[q0 * CC + c0]      = acc00[r] * inv;
                ob[q0 * CC + c0 + 32] = acc01[r] * inv;
            }
            if (q1 < NQ){
                float inv = 1.0f / sL[q1];
                ob[q1 * CC + c0]      = acc10[r] * inv;
                ob[q1 * CC + c0 + 32] = acc11[r] * inv;
            }
        }
    } else {
        float* ob = po + ((size_t)bn * split + seg) * PO_PER;
#pragma unroll
        for (int r = 0; r < 16; ++r){
            int row = (r & 3) + 8 * (r >> 2) + 4 * (lane >> 5);
            int q0 = mp * 64 + row, q1 = q0 + 32;
            if (q0 < NQ){
                ob[q0 * CC + c0]      = acc00[r];
                ob[q0 * CC + c0 + 32] = acc01[r];
            }
            if (q1 < NQ){
                ob[q1 * CC + c0]      = acc10[r];
                ob[q1 * CC + c0 + 32] = acc11[r];
            }
        }
        if (tid < 128) pl[((size_t)bn * split + seg) * 128 + tid] = sL[tid];
    }
}

// ---------------------------------------------------------------------------
// Phase B: sum partials across segments, normalize, write out.
// grid = 392 (2 wgs per bn), 512 threads.
// ---------------------------------------------------------------------------
__global__ __launch_bounds__(512) void reduce_kernel(
        const float* __restrict__ po, const float* __restrict__ pl,
        float* __restrict__ out, int split)
{
    __shared__ float sInv[64];
    const int bn = blockIdx.x >> 1, hf = blockIdx.x & 1, tid = threadIdx.x;
    if (tid < 50){
        int q = hf * 50 + tid;
        float s = 0.f;
        for (int g = 0; g < split; ++g)
            s += pl[((size_t)bn * split + g) * 128 + q];
        sInv[tid] = 1.0f / s;
    }
    __syncthreads();
    const float* base = po + (size_t)bn * split * PO_PER;
    float* ob = out + (size_t)bn * PO_PER;
#pragma unroll 1
    for (int i = 0; i < 25; ++i){
        int idx = hf * 12800 + i * 512 + tid;
        float s = 0.f;
        for (int g = 0; g < split; ++g) s += base[g * PO_PER + idx];
        ob[idx] = s * sInv[(idx >> 8) - hf * 50];
    }
}

extern "C" void kernel_launch(void* const* d_in, const int* in_sizes, int n_in,
                              void* d_out, int out_size, void* d_ws, size_t ws_size,
                              hipStream_t stream){
    const float* img = (const float*)d_in[0];
    const float* Qg  = (const float*)d_in[1];
    float* out = (float*)d_out;

    uint4* qf = (uint4*)d_ws;
    qfrag_kernel<<<8, 512, 0, stream>>>(Qg, qf);

    int split = 1;
    const size_t per_seg = (size_t)196 * (PO_PER + 128) * sizeof(float);
    if (ws_size >= QF_BYTES + 4 * per_seg) split = 4;

    float *po = nullptr, *pl = nullptr;
    if (split > 1){
        po = (float*)((char*)d_ws + QF_BYTES);
        pl = po + (size_t)196 * split * PO_PER;
    }

    attn_kernel<<<196 * split, 512, 0, stream>>>(img, qf, out, po, pl, split);
    if (split > 1)
        reduce_kernel<<<392, 512, 0, stream>>>(po, pl, out, split);
}

// Round 10
// 335.382 us; speedup vs baseline: 1.4059x; 1.0559x over previous
//
#include <hip/hip_runtime.h>
#include <stdint.h>

typedef short short8 __attribute__((ext_vector_type(8)));
typedef __fp16 fp16x8 __attribute__((ext_vector_type(8)));
typedef float f32x16 __attribute__((ext_vector_type(16)));
typedef unsigned int uint;

#define NREG 49
#define NQ   100
#define CC   256
#define OUT_POS_OFF 5017600        // 4*49*100*256
#define PO_PER (NQ*CC)             // 25600 floats per partial slot
#define QF_BYTES 65536             // 64 frags * 64 lanes * 16 B (fp16)
#define NBLK 256                   // persistent grid: one block per CU
#define NSLOT (NBLK*2)             // <=2 partial slots per block
#define MFMA_BF16 __builtin_amdgcn_mfma_f32_32x32x16_bf16
#define MFMA_F16  __builtin_amdgcn_mfma_f32_32x32x16_f16

union U4H8 { uint4 u; fp16x8 h; short8 s; };

// LDS-only barrier: global loads stay in flight across it.
#define LBAR() do { \
    asm volatile("s_waitcnt lgkmcnt(0)" ::: "memory"); \
    __builtin_amdgcn_s_barrier(); \
} while (0)

__device__ __forceinline__ uint pkrtz(float a, float b){
    auto v = __builtin_amdgcn_cvt_pkrtz(a, b);   // __fp16 x2, RTZ
    return __builtin_bit_cast(uint, v);
}
__device__ __forceinline__ uint16_t f2bf_rne(float x){
    uint u = __float_as_uint(x);
    u += 0x7fffu + ((u >> 16) & 1u);
    return (uint16_t)(u >> 16);
}
__device__ __forceinline__ float bf2f(uint16_t b){
    return __uint_as_float(((uint)b) << 16);
}

// ---------------------------------------------------------------------------
// Kernel 0: Q fragments in fp16, exact 32x32x16 B-operand order.
// ---------------------------------------------------------------------------
__global__ __launch_bounds__(512) void qfrag_kernel(const float* __restrict__ Qg,
                                                    uint4* __restrict__ qf){
    int gid  = blockIdx.x * 512 + threadIdx.x;   // 0..4095
    int lane = gid & 63;
    int frag = gid >> 6;                         // 0..63
    int k    = frag & 15;
    int qt   = frag >> 4;
    int q    = qt * 32 + (lane & 31);
    int c0   = k * 16 + (lane >> 5) * 8;
    float v[8];
#pragma unroll
    for (int j = 0; j < 8; ++j) v[j] = (q < NQ) ? Qg[q * CC + c0 + j] : 0.f;
    qf[gid] = make_uint4(pkrtz(v[0], v[1]), pkrtz(v[2], v[3]),
                         pkrtz(v[4], v[5]), pkrtz(v[6], v[7]));
}

// ---------------------------------------------------------------------------
// Phase A: persistent fused attention. Grid = 256 blocks (1/CU, 1 round).
// Work = 3136 chunk-units (196 bn x 16 chunks); block b takes 12+(b<64)
// CONTIGUOUS units (<=2 distinct bn), flushing acc -> po slot on bn change.
// Compute core = R8 (coalesced loads; sAf swizzled; sRT scatter; 4 LBARs).
// ---------------------------------------------------------------------------
__global__ __launch_bounds__(512, 2) void attn_kernel(
        const float* __restrict__ img, const uint4* __restrict__ qf,
        float* __restrict__ out, float* __restrict__ po,
        float* __restrict__ pl, int* __restrict__ tg)
{
    __shared__ __align__(16) unsigned char smem[65536];
    unsigned char* sRT = smem;
    unsigned char* sU  = smem + 32768;

    const int tid = threadIdx.x;
    const int b   = blockIdx.x;

    if (b == 0 && tid < NREG){    // positions output
        out[OUT_POS_OFF + 2 * tid]     = (float)((tid / 7) / 7.0);
        out[OUT_POS_OFF + 2 * tid + 1] = (float)((tid % 7) / 7.0);
    }

    const int lane = tid & 63, w = tid >> 6;
    const int l31  = lane & 31;
    const int st = w & 1, qt = w >> 1;     // GEMM1 roles
    const int mp = w & 1, cq = w >> 1;     // GEMM2 roles
    const int c0 = cq * 64 + l31;          // epilogue channel

    // staging roles (coalesced ownership, R8)
    const int kA    = lane >> 2;
    const int aInP  = 32 * ((lane >> 1) & 1) * 16 + (lane & 1) * 8;
    const int aSwz  = (kA & 7) << 4;
    const int cb    = lane >> 3;
    const int c31b  = 4 * (lane & 7);

    // Q fragments in registers (fp16): 16 x 16B
    uint4 qr[16];
#pragma unroll
    for (int k = 0; k < 16; ++k) qr[k] = qf[(qt * 16 + k) * 64 + lane];

    f32x16 acc00, acc01, acc10, acc11;
#pragma unroll
    for (int i = 0; i < 16; ++i){ acc00[i]=0.f; acc01[i]=0.f; acc10[i]=0.f; acc11[i]=0.f; }
    float lp = 0.f;
    const int qq = qt * 32 + l31;

    // contiguous unit range for this block
    const int cnt = 12 + (b < 64 ? 1 : 0);
    const int u0  = b * 12 + (b < 64 ? b : 64);
    const int u1  = u0 + cnt;

    auto rebase = [&](int u) -> const float* {
        int bn = u >> 4;
        int rr = bn % NREG, bb = bn / NREG;
        int gh = rr / 7,    gw = rr % 7;
        return img + ((size_t)(bb * 224 + gh * 32) * 224 + gw * 32) * CC;
    };

    auto flush = [&](int bn_, int fi_){
        __syncthreads();                       // all LDS reads of sU done
        float* sL = (float*)sU;
        if (tid < 128) sL[tid] = 0.f;
        __syncthreads();
        atomicAdd(&sL[qq], lp);
        __syncthreads();
        const int slot = b * 2 + fi_;
        float* ob = po + (size_t)slot * PO_PER;
#pragma unroll
        for (int r = 0; r < 16; ++r){
            int row = (r & 3) + 8 * (r >> 2) + 4 * (lane >> 5);
            int q0 = mp * 64 + row, q1 = q0 + 32;
            if (q0 < NQ){
                ob[q0 * CC + c0]      = acc00[r];
                ob[q0 * CC + c0 + 32] = acc01[r];
            }
            if (q1 < NQ){
                ob[q1 * CC + c0]      = acc10[r];
                ob[q1 * CC + c0 + 32] = acc11[r];
            }
        }
        if (tid < 128) pl[(size_t)slot * 128 + tid] = sL[tid];
        if (tid == 0)  tg[slot] = bn_;
        __syncthreads();                       // sL reads done before sU reuse
    };

    float4 rb[8], rb2[8];
    {   // preload first unit (coalesced: instruction j = one pixel's 1 KB)
        const float* rbase = rebase(u0);
        int ch = u0 & 15;
#pragma unroll
        for (int j = 0; j < 8; ++j){
            int p = ch * 64 + j * 8 + w;
            rb[j] = *(const float4*)(rbase + ((p >> 5) * 224 + (p & 31)) * CC + 4 * lane);
        }
    }

    int cur_bn = u0 >> 4, fi = 0;

    for (int u = u0; u < u1; ++u){
        int bn = u >> 4;
        if (bn != cur_bn){
            flush(cur_bn, fi);
            fi = 1; cur_bn = bn;
#pragma unroll
            for (int i = 0; i < 16; ++i){ acc00[i]=0.f; acc01[i]=0.f; acc10[i]=0.f; acc11[i]=0.f; }
            lp = 0.f;
        }

        // ---- stage: rb -> sAf (fp16, b64 swizzled) + sRT (bf16 scatter) ----
#pragma unroll
        for (int j = 0; j < 8; ++j){
            int pl_ = j * 8 + w;                       // local pixel 0..63
            int frag  = (pl_ >> 5) * 16 + kA;
            int inner = (((pl_ & 31) * 16 + aInP)) ^ aSwz;
            uint2 val = make_uint2(pkrtz(rb[j].x, rb[j].y), pkrtz(rb[j].z, rb[j].w));
            *(uint2*)(sU + frag * 1024 + inner) = val;
            const float* fv = (const float*)&rb[j];
            int fbase = ((j >> 1) * 8 + cb) * 1024 + (j & 1) * 512 + w * 2;
#pragma unroll
            for (int cc = 0; cc < 4; ++cc){
                uint uu = __float_as_uint(fv[cc]);
                *(uint16_t*)(sRT + fbase + (((c31b + cc) ^ cb) << 4)) = (uint16_t)(uu >> 16);
            }
        }

        // ---- prefetch next unit (coalesced; in flight across barriers) ----
        if (u + 1 < u1){
            const float* rbase2 = rebase(u + 1);
            int ch2 = (u + 1) & 15;
#pragma unroll
            for (int j = 0; j < 8; ++j){
                int p = ch2 * 64 + j * 8 + w;
                rb2[j] = *(const float4*)(rbase2 + ((p >> 5) * 224 + (p & 31)) * CC + 4 * lane);
            }
        }
        LBAR();   // B1: staged LDS data visible (vmcnt NOT drained)

        // ---- GEMM1 (fp16): scoresT[s][q], wave (st, qt) ----
        f32x16 a1;
#pragma unroll
        for (int i = 0; i < 16; ++i) a1[i] = 0.f;
#pragma unroll
        for (int k = 0; k < 16; ++k){
            U4H8 af; af.u = *(const uint4*)(sU + (st * 16 + k) * 1024 + ((lane * 16) ^ ((k & 7) << 4)));
            U4H8 bq; bq.u = qr[k];
            a1 = MFMA_F16(af.h, bq.h, a1, 0, 0, 0);
        }
        LBAR();   // B2: GEMM1 reads of sAf done before sP overwrites

        // ---- exp(score-40) -> bf16 sP (GEMM2-A frag-order), accumulate l ----
#pragma unroll
        for (int g2 = 0; g2 < 4; ++g2){
            uint16_t e[4];
#pragma unroll
            for (int r2 = 0; r2 < 4; ++r2){
                float sc = a1[g2 * 4 + r2];
                float pv = exp2f(sc * 1.4426950408889634f - 57.70780163555852f);
                e[r2] = f2bf_rne(pv);
                lp += bf2f(e[r2]);
            }
            int kst = st * 2 + (g2 >> 1);
            int boff = ((kst * 4 + qt) * 64 + (g2 & 1) * 32 + l31) * 16 + (lane >> 5) * 8;
            *(uint2*)(sU + boff) = make_uint2((uint)e[0] | ((uint)e[1] << 16),
                                              (uint)e[2] | ((uint)e[3] << 16));
        }
        LBAR();   // B3: sP visible

        // ---- GEMM2 (bf16): O[q][c] += P * R, wave (mp, cq) ----
#pragma unroll
        for (int ks = 0; ks < 4; ++ks){
            U4H8 A0, A1, B0, B1;
            A0.u = *(const uint4*)(sU  + ((ks * 4 + mp * 2    ) * 64 + lane) * 16);
            A1.u = *(const uint4*)(sU  + ((ks * 4 + mp * 2 + 1) * 64 + lane) * 16);
            B0.u = *(const uint4*)(sRT + ((ks * 8 + cq * 2    ) * 64 + (lane ^ (cq * 2    ))) * 16);
            B1.u = *(const uint4*)(sRT + ((ks * 8 + cq * 2 + 1) * 64 + (lane ^ (cq * 2 + 1))) * 16);
            acc00 = MFMA_BF16(A0.s, B0.s, acc00, 0, 0, 0);
            acc01 = MFMA_BF16(A0.s, B1.s, acc01, 0, 0, 0);
            acc10 = MFMA_BF16(A1.s, B0.s, acc10, 0, 0, 0);
            acc11 = MFMA_BF16(A1.s, B1.s, acc11, 0, 0, 0);
        }
        LBAR();   // B4: GEMM2 reads done before next stage writes

        if (u + 1 < u1){
#pragma unroll
            for (int j = 0; j < 8; ++j) rb[j] = rb2[j];
        }
    }

    flush(cur_bn, fi);
    if (fi == 0 && tid == 0) tg[b * 2 + 1] = -1;   // unused second slot
}

// ---------------------------------------------------------------------------
// Phase B: gather partial slots by tag, sum, normalize, write out.
// grid = 392 (2 wgs per bn), 512 threads.
// ---------------------------------------------------------------------------
__global__ __launch_bounds__(512) void reduce_kernel(
        const float* __restrict__ po, const float* __restrict__ pl,
        const int* __restrict__ tg, float* __restrict__ out)
{
    __shared__ int slots[8];
    __shared__ int ns;
    __shared__ float sInv[64];
    const int bn = blockIdx.x >> 1, hf = blockIdx.x & 1, tid = threadIdx.x;

    if (tid == 0) ns = 0;
    __syncthreads();
    if (tid < NSLOT && tg[tid] == bn){
        int i = atomicAdd(&ns, 1);
        slots[i] = tid;
    }
    __syncthreads();
    const int n = ns;

    if (tid < 50){
        int q = hf * 50 + tid;
        float s = 0.f;
        for (int i = 0; i < n; ++i)
            s += pl[(size_t)slots[i] * 128 + q];
        sInv[tid] = 1.0f / s;
    }
    __syncthreads();

    float* ob = out + (size_t)bn * PO_PER;
#pragma unroll 1
    for (int i = 0; i < 25; ++i){
        int idx = hf * 12800 + i * 512 + tid;
        float s = 0.f;
        for (int j = 0; j < n; ++j)
            s += po[(size_t)slots[j] * PO_PER + idx];
        ob[idx] = s * sInv[(idx >> 8) - hf * 50];
    }
}

extern "C" void kernel_launch(void* const* d_in, const int* in_sizes, int n_in,
                              void* d_out, int out_size, void* d_ws, size_t ws_size,
                              hipStream_t stream){
    const float* img = (const float*)d_in[0];
    const float* Qg  = (const float*)d_in[1];
    float* out = (float*)d_out;

    uint4* qf = (uint4*)d_ws;
    float* po = (float*)((char*)d_ws + QF_BYTES);
    float* pl = po + (size_t)NSLOT * PO_PER;
    int*   tg = (int*)(pl + (size_t)NSLOT * 128);
    // footprint: 64 KB + 52.4 MB + 256 KB + 2 KB  (< the >=80 MB ws observed)

    qfrag_kernel<<<8, 512, 0, stream>>>(Qg, qf);
    attn_kernel<<<NBLK, 512, 0, stream>>>(img, qf, out, po, pl, tg);
    reduce_kernel<<<392, 512, 0, stream>>>(po, pl, tg, out);
}